// Round 8
// baseline (249.796 us; speedup 1.0000x reference)
//
#include <hip/hip_runtime.h>
#include <hip/hip_bf16.h>

typedef __bf16 bf16_t;
typedef __bf16 bf16x8 __attribute__((ext_vector_type(8)));
typedef __bf16 bf16x4 __attribute__((ext_vector_type(4)));
typedef float f32x4 __attribute__((ext_vector_type(4)));

#define B_ 2
#define L_ 1024
#define D_ 1024
#define H_ 16
#define HD_ 64

// ---------------------------------------------------------------------------
// fp32 -> bf16 cast, 4 elems/thread
// ---------------------------------------------------------------------------
__global__ __launch_bounds__(256) void cast_kernel(const float* __restrict__ src,
                                                   bf16_t* __restrict__ dst,
                                                   int n4) {
    int i = blockIdx.x * 256 + threadIdx.x;
    if (i < n4) {
        const float4 v = ((const float4*)src)[i];
        bf16x4 o;
        o[0] = (bf16_t)v.x; o[1] = (bf16_t)v.y;
        o[2] = (bf16_t)v.z; o[3] = (bf16_t)v.w;
        ((bf16x4*)dst)[i] = o;
    }
}

// ---------------------------------------------------------------------------
// E (fp32, 2047x64) -> Eb (bf16, 2048x64) with a prepended zero row.
// rel[i,j] = q_i . E[j-i+L-2]; zero exactly at j-i = 1-L  =>  Eb[j-i+L-1]
// ---------------------------------------------------------------------------
__global__ __launch_bounds__(256) void conv_e_kernel(const float* __restrict__ E,
                                                     bf16_t* __restrict__ Eb) {
    int idx = blockIdx.x * 256 + threadIdx.x;
    if (idx < 64) Eb[idx] = (bf16_t)0.f;
    if (idx < 2047 * 64) Eb[64 + idx] = (bf16_t)E[idx];
}

// ---------------------------------------------------------------------------
// Fused QKV GEMM: blockIdx.z in {0,1,2} selects (Wq,bq)->qbh, (Wk,bk)->kbh,
// (Wv,bv)->vtb (transposed per-head layout vtb[bh][d][j]).
// 64x64 tile, BK=64, bf16 MFMA (layouts HW-validated r2==r4).
// ---------------------------------------------------------------------------
__global__ __launch_bounds__(256) void qkv_gemm_kernel(
    const bf16_t* __restrict__ xb,
    const bf16_t* __restrict__ Wqb, const bf16_t* __restrict__ Wkb,
    const bf16_t* __restrict__ Wvb,
    const float* __restrict__ bq, const float* __restrict__ bk2,
    const float* __restrict__ bv2,
    bf16_t* __restrict__ qbh, bf16_t* __restrict__ kbh,
    bf16_t* __restrict__ vtb) {
    constexpr int K = D_;
    __shared__ __align__(16) bf16_t As[64][72];
    __shared__ __align__(16) bf16_t Bs[64][72];

    const int z = blockIdx.z;
    const bf16_t* W = (z == 0) ? Wqb : (z == 1) ? Wkb : Wvb;
    const float* bias = (z == 0) ? bq : (z == 1) ? bk2 : bv2;
    const float alpha = (z == 0) ? 0.125f : 1.0f;   // hd^-0.5 folded into q

    const int tid = threadIdx.x;
    const int m0 = blockIdx.y * 64;
    const int n0 = blockIdx.x * 64;
    const int wave = tid >> 6;
    const int lane = tid & 63;
    const int wm = (wave >> 1) << 5;
    const int wn = (wave & 1) << 5;
    const int lrow = lane & 15;
    const int quad = lane >> 4;
    const int r0 = tid >> 3;          // 0..31
    const int c8 = (tid & 7) << 3;    // 0..56

    f32x4 acc[2][2] = {};

    for (int k0 = 0; k0 < K; k0 += 64) {
        *(uint4*)&As[r0][c8]      = *(const uint4*)&xb[(size_t)(m0 + r0) * K + k0 + c8];
        *(uint4*)&As[r0 + 32][c8] = *(const uint4*)&xb[(size_t)(m0 + r0 + 32) * K + k0 + c8];
        *(uint4*)&Bs[r0][c8]      = *(const uint4*)&W[(size_t)(n0 + r0) * K + k0 + c8];
        *(uint4*)&Bs[r0 + 32][c8] = *(const uint4*)&W[(size_t)(n0 + r0 + 32) * K + k0 + c8];
        __syncthreads();

#pragma unroll
        for (int kc = 0; kc < 2; ++kc) {
            bf16x8 af[2], bfr[2];
            af[0]  = *(const bf16x8*)&As[wm + lrow][kc * 32 + 8 * quad];
            af[1]  = *(const bf16x8*)&As[wm + 16 + lrow][kc * 32 + 8 * quad];
            bfr[0] = *(const bf16x8*)&Bs[wn + lrow][kc * 32 + 8 * quad];
            bfr[1] = *(const bf16x8*)&Bs[wn + 16 + lrow][kc * 32 + 8 * quad];
#pragma unroll
            for (int t = 0; t < 2; ++t)
#pragma unroll
                for (int u = 0; u < 2; ++u)
                    acc[t][u] = __builtin_amdgcn_mfma_f32_16x16x32_bf16(
                        af[t], bfr[u], acc[t][u], 0, 0, 0);
        }
        __syncthreads();
    }

#pragma unroll
    for (int t = 0; t < 2; ++t) {
#pragma unroll
        for (int u = 0; u < 2; ++u) {
            const int col = n0 + wn + u * 16 + lrow;
            const float bvv = bias[col];
            const int h = col >> 6, d = col & 63;
            if (z < 2) {
                bf16_t* outp = z ? kbh : qbh;
#pragma unroll
                for (int r = 0; r < 4; ++r) {
                    const int row = m0 + wm + t * 16 + quad * 4 + r;
                    const int b = row >> 10, i = row & 1023;
                    outp[((size_t)((b * H_ + h) * L_ + i)) * HD_ + d] =
                        (bf16_t)((acc[t][u][r] + bvv) * alpha);
                }
            } else {
                const int row0 = m0 + wm + t * 16 + quad * 4;
                const int b = row0 >> 10, i = row0 & 1023;
                bf16x4 pk;
#pragma unroll
                for (int r = 0; r < 4; ++r) pk[r] = (bf16_t)(acc[t][u][r] + bvv);
                *(bf16x4*)&vtb[((size_t)((b * H_ + h) * HD_ + d)) * L_ + i] = pk;
            }
        }
    }
}

// ---------------------------------------------------------------------------
// Wo GEMM: out[m][n] = sum_k ctxb[m][k]*Wob[n][k] + bo[n], fp32 out.
// ---------------------------------------------------------------------------
__global__ __launch_bounds__(256) void out_gemm_kernel(
    const bf16_t* __restrict__ A, const bf16_t* __restrict__ W,
    const float* __restrict__ bias, float* __restrict__ outF) {
    constexpr int K = D_;
    __shared__ __align__(16) bf16_t As[64][72];
    __shared__ __align__(16) bf16_t Bs[64][72];

    const int tid = threadIdx.x;
    const int m0 = blockIdx.y * 64;
    const int n0 = blockIdx.x * 64;
    const int wave = tid >> 6;
    const int lane = tid & 63;
    const int wm = (wave >> 1) << 5;
    const int wn = (wave & 1) << 5;
    const int lrow = lane & 15;
    const int quad = lane >> 4;
    const int r0 = tid >> 3;
    const int c8 = (tid & 7) << 3;

    f32x4 acc[2][2] = {};

    for (int k0 = 0; k0 < K; k0 += 64) {
        *(uint4*)&As[r0][c8]      = *(const uint4*)&A[(size_t)(m0 + r0) * K + k0 + c8];
        *(uint4*)&As[r0 + 32][c8] = *(const uint4*)&A[(size_t)(m0 + r0 + 32) * K + k0 + c8];
        *(uint4*)&Bs[r0][c8]      = *(const uint4*)&W[(size_t)(n0 + r0) * K + k0 + c8];
        *(uint4*)&Bs[r0 + 32][c8] = *(const uint4*)&W[(size_t)(n0 + r0 + 32) * K + k0 + c8];
        __syncthreads();

#pragma unroll
        for (int kc = 0; kc < 2; ++kc) {
            bf16x8 af[2], bfr[2];
            af[0]  = *(const bf16x8*)&As[wm + lrow][kc * 32 + 8 * quad];
            af[1]  = *(const bf16x8*)&As[wm + 16 + lrow][kc * 32 + 8 * quad];
            bfr[0] = *(const bf16x8*)&Bs[wn + lrow][kc * 32 + 8 * quad];
            bfr[1] = *(const bf16x8*)&Bs[wn + 16 + lrow][kc * 32 + 8 * quad];
#pragma unroll
            for (int t = 0; t < 2; ++t)
#pragma unroll
                for (int u = 0; u < 2; ++u)
                    acc[t][u] = __builtin_amdgcn_mfma_f32_16x16x32_bf16(
                        af[t], bfr[u], acc[t][u], 0, 0, 0);
        }
        __syncthreads();
    }

#pragma unroll
    for (int t = 0; t < 2; ++t) {
#pragma unroll
        for (int u = 0; u < 2; ++u) {
            const int col = n0 + wn + u * 16 + lrow;
            const float bvv = bias[col];
#pragma unroll
            for (int r = 0; r < 4; ++r) {
                const int row = m0 + wm + t * 16 + quad * 4 + r;
                outF[(size_t)row * D_ + col] = acc[t][u][r] + bvv;
            }
        }
    }
}

// ---------------------------------------------------------------------------
// MFMA flash attention, barrier-free main loop.
// Wave = (bh, 16 Q-rows, K-quarter of 256). Block = 4 waves (the 4 quarters).
// K and V^T B-frags load directly from global (vtb is pre-transposed).
// rel via R = Q @ Eband^T (80-wide) + wave-private LDS skew. Online softmax
// in registers. Final 4-way merge via LDS (2 barriers total).
// ---------------------------------------------------------------------------
__global__ __launch_bounds__(256) void fattn_kernel(
    const bf16_t* __restrict__ qbh, const bf16_t* __restrict__ kbh,
    const bf16_t* __restrict__ vtb, const bf16_t* __restrict__ Eb,
    bf16_t* __restrict__ ctx) {
    // loop phase: RP[4][16][88] bf16 (11264 B), wave-private rows.
    // merge phase (after barrier): Om[4][16][64] f32 (16384 B) | ml (512 B).
    __shared__ __align__(16) char smem[16896];
    bf16_t (*RP)[16][88] = (bf16_t(*)[16][88])smem;
    float  (*Om)[16][64] = (float(*)[16][64])smem;
    float  (*ml)[16][2]  = (float(*)[16][2])(smem + 16384);

    const int tid = threadIdx.x;
    const int w = tid >> 6;          // wave = K-quarter
    const int lane = tid & 63;
    const int q4 = lane >> 4;
    const int n = lane & 15;
    const int bh = blockIdx.y;
    const int b = bh >> 4;
    const int h = bh & 15;
    const int ib = blockIdx.x * 16;  // Q-row base (shared by all 4 waves)

    // Q A-fragments (16 rows), held all kernel.
    bf16x8 aq[2];
    {
        const bf16x8* qrow = (const bf16x8*)(qbh + ((size_t)bh * L_ + ib + n) * HD_);
        aq[0] = qrow[q4];
        aq[1] = qrow[4 + q4];
    }

    const bf16_t* vbase = vtb + (size_t)bh * HD_ * L_;

    f32x4 o[4] = {};
    float m_r[4] = {-1e30f, -1e30f, -1e30f, -1e30f};
    float l_r[4] = {0.f, 0.f, 0.f, 0.f};

    for (int t = 0; t < 4; ++t) {
        const int j0 = w * 256 + t * 64;

        // ---- S = Q K^T ----
        f32x4 s[4] = {};
#pragma unroll
        for (int u = 0; u < 4; ++u) {
#pragma unroll
            for (int kc = 0; kc < 2; ++kc) {
                const bf16x8 bk = *(const bf16x8*)(kbh +
                    ((size_t)bh * L_ + j0 + 16 * u + n) * HD_ + kc * 32 + 8 * q4);
                s[u] = __builtin_amdgcn_mfma_f32_16x16x32_bf16(aq[kc], bk, s[u], 0, 0, 0);
            }
        }

        // ---- R = Q @ Eband^T (rows rbase..rbase+79); p = jj-row+15 in [0,78] ----
        const int rbase = j0 - ib + 1008;
#pragma unroll
        for (int up = 0; up < 5; ++up) {
            f32x4 rc = {};
#pragma unroll
            for (int kc = 0; kc < 2; ++kc) {
                const bf16x8 be = *(const bf16x8*)(Eb +
                    ((size_t)(rbase + 16 * up + n)) * HD_ + kc * 32 + 8 * q4);
                rc = __builtin_amdgcn_mfma_f32_16x16x32_bf16(aq[kc], be, rc, 0, 0, 0);
            }
#pragma unroll
            for (int r = 0; r < 4; ++r)
                RP[w][4 * q4 + r][16 * up + n] = (bf16_t)rc[r];
        }

        // ---- skew add: S[row][jj] += R[row][jj - row + 15] ----
#pragma unroll
        for (int u = 0; u < 4; ++u)
#pragma unroll
            for (int r = 0; r < 4; ++r)
                s[u][r] += (float)RP[w][4 * q4 + r][16 * u + n - (4 * q4 + r) + 15];

        // ---- online softmax (rows across 16-lane groups) ----
#pragma unroll
        for (int r = 0; r < 4; ++r) {
            float mt = fmaxf(fmaxf(s[0][r], s[1][r]), fmaxf(s[2][r], s[3][r]));
            mt = fmaxf(mt, __shfl_xor(mt, 1));
            mt = fmaxf(mt, __shfl_xor(mt, 2));
            mt = fmaxf(mt, __shfl_xor(mt, 4));
            mt = fmaxf(mt, __shfl_xor(mt, 8));
            const float mn = fmaxf(m_r[r], mt);
            const float al = __expf(m_r[r] - mn);
            m_r[r] = mn;
            float ps = 0.f;
#pragma unroll
            for (int u = 0; u < 4; ++u) {
                const float pv = __expf(s[u][r] - mn);
                s[u][r] = pv;
                ps += pv;
            }
            ps += __shfl_xor(ps, 1);
            ps += __shfl_xor(ps, 2);
            ps += __shfl_xor(ps, 4);
            ps += __shfl_xor(ps, 8);
            l_r[r] = l_r[r] * al + ps;
#pragma unroll
            for (int u = 0; u < 4; ++u) o[u][r] *= al;
        }

        // ---- P -> LDS (own-wave rows), then A-frags ----
#pragma unroll
        for (int u = 0; u < 4; ++u)
#pragma unroll
            for (int r = 0; r < 4; ++r)
                RP[w][4 * q4 + r][16 * u + n] = (bf16_t)s[u][r];

        bf16x8 pa[2];
        pa[0] = *(const bf16x8*)&RP[w][n][8 * q4];
        pa[1] = *(const bf16x8*)&RP[w][n][32 + 8 * q4];

        // ---- O += P V  (B-frags straight from pre-transposed vtb) ----
#pragma unroll
        for (int u = 0; u < 4; ++u) {
#pragma unroll
            for (int kc = 0; kc < 2; ++kc) {
                const bf16x8 bv = *(const bf16x8*)(vbase +
                    ((size_t)(16 * u + n)) * L_ + j0 + kc * 32 + 8 * q4);
                o[u] = __builtin_amdgcn_mfma_f32_16x16x32_bf16(pa[kc], bv, o[u], 0, 0, 0);
            }
        }
    }

    // ---- 4-way cross-wave merge ----
    __syncthreads();   // all waves done with RP before Om alias writes
#pragma unroll
    for (int u = 0; u < 4; ++u)
#pragma unroll
        for (int r = 0; r < 4; ++r)
            Om[w][4 * q4 + r][16 * u + n] = o[u][r];
    if (n == 0) {
#pragma unroll
        for (int r = 0; r < 4; ++r) {
            ml[w][4 * q4 + r][0] = m_r[r];
            ml[w][4 * q4 + r][1] = l_r[r];
        }
    }
    __syncthreads();

    {
        const int row = tid >> 4;     // 0..15
        const int nc = tid & 15;
        float m0v = ml[0][row][0], m1v = ml[1][row][0];
        float m2v = ml[2][row][0], m3v = ml[3][row][0];
        const float ms = fmaxf(fmaxf(m0v, m1v), fmaxf(m2v, m3v));
        const float a0 = __expf(m0v - ms), a1 = __expf(m1v - ms);
        const float a2 = __expf(m2v - ms), a3 = __expf(m3v - ms);
        const float inv = 1.f / (a0 * ml[0][row][1] + a1 * ml[1][row][1] +
                                 a2 * ml[2][row][1] + a3 * ml[3][row][1]);
#pragma unroll
        for (int u = 0; u < 4; ++u) {
            const int col = nc + 16 * u;
            const float val = (a0 * Om[0][row][col] + a1 * Om[1][row][col] +
                               a2 * Om[2][row][col] + a3 * Om[3][row][col]) * inv;
            ctx[((size_t)(b * L_ + ib + row)) * D_ + h * HD_ + col] = (bf16_t)val;
        }
    }
}

// ---------------------------------------------------------------------------
extern "C" void kernel_launch(void* const* d_in, const int* in_sizes, int n_in,
                              void* d_out, int out_size, void* d_ws,
                              size_t ws_size, hipStream_t stream) {
    const float* x   = (const float*)d_in[0];
    const float* Wq  = (const float*)d_in[1];
    const float* bq  = (const float*)d_in[2];
    const float* Wk  = (const float*)d_in[3];
    const float* bk  = (const float*)d_in[4];
    const float* Wv  = (const float*)d_in[5];
    const float* bv  = (const float*)d_in[6];
    const float* Wo  = (const float*)d_in[7];
    const float* bo  = (const float*)d_in[8];
    const float* E   = (const float*)d_in[9];
    float* out = (float*)d_out;   // fp32 per reference (validated round 5)

    char* ws = (char*)d_ws;
    const size_t MB = 1024u * 1024u;
    bf16_t* xb   = (bf16_t*)(ws);             // 4 MB (2048x1024)
    bf16_t* Wqb  = (bf16_t*)(ws + 4 * MB);    // 2 MB
    bf16_t* Wkb  = (bf16_t*)(ws + 6 * MB);    // 2 MB
    bf16_t* Wvb  = (bf16_t*)(ws + 8 * MB);    // 2 MB
    bf16_t* Wob  = (bf16_t*)(ws + 10 * MB);   // 2 MB
    bf16_t* qbh  = (bf16_t*)(ws + 12 * MB);   // 4 MB (BH,L,64), pre-scaled
    bf16_t* kbh  = (bf16_t*)(ws + 16 * MB);   // 4 MB (BH,L,64)
    bf16_t* vtb  = (bf16_t*)(ws + 20 * MB);   // 4 MB (BH,64,L) transposed
    bf16_t* ctxb = (bf16_t*)(ws + 24 * MB);   // 4 MB (B,L,D)
    bf16_t* Eb   = (bf16_t*)(ws + 28 * MB);   // 0.25 MB (2048x64)

    conv_e_kernel<<<512, 256, 0, stream>>>(E, Eb);
    cast_kernel<<<2048, 256, 0, stream>>>(x, xb, (B_ * L_ * D_) / 4);
    cast_kernel<<<1024, 256, 0, stream>>>(Wq, Wqb, (D_ * D_) / 4);
    cast_kernel<<<1024, 256, 0, stream>>>(Wk, Wkb, (D_ * D_) / 4);
    cast_kernel<<<1024, 256, 0, stream>>>(Wv, Wvb, (D_ * D_) / 4);
    cast_kernel<<<1024, 256, 0, stream>>>(Wo, Wob, (D_ * D_) / 4);

    dim3 gq(D_ / 64, (B_ * L_) / 64, 3);  // (16, 32, 3) = 1536 blocks
    qkv_gemm_kernel<<<gq, 256, 0, stream>>>(xb, Wqb, Wkb, Wvb, bq, bk, bv,
                                            qbh, kbh, vtb);

    dim3 ga(L_ / 16, B_ * H_);  // (64, 32) = 2048 blocks
    fattn_kernel<<<ga, 256, 0, stream>>>(qbh, kbh, vtb, Eb, ctxb);

    dim3 gg(D_ / 64, (B_ * L_) / 64);  // (16, 32)
    out_gemm_kernel<<<gg, 256, 0, stream>>>(ctxb, Wob, bo, out);
}

// Round 9
// 210.138 us; speedup vs baseline: 1.1887x; 1.1887x over previous
//
#include <hip/hip_runtime.h>
#include <hip/hip_bf16.h>

typedef __bf16 bf16_t;
typedef __bf16 bf16x8 __attribute__((ext_vector_type(8)));
typedef __bf16 bf16x4 __attribute__((ext_vector_type(4)));
typedef float f32x4 __attribute__((ext_vector_type(4)));

#define B_ 2
#define L_ 1024
#define D_ 1024
#define H_ 16
#define HD_ 64

// ---------------------------------------------------------------------------
// fp32 -> bf16 cast, 4 elems/thread
// ---------------------------------------------------------------------------
__global__ __launch_bounds__(256) void cast_kernel(const float* __restrict__ src,
                                                   bf16_t* __restrict__ dst,
                                                   int n4) {
    int i = blockIdx.x * 256 + threadIdx.x;
    if (i < n4) {
        const float4 v = ((const float4*)src)[i];
        bf16x4 o;
        o[0] = (bf16_t)v.x; o[1] = (bf16_t)v.y;
        o[2] = (bf16_t)v.z; o[3] = (bf16_t)v.w;
        ((bf16x4*)dst)[i] = o;
    }
}

// 4 weight matrices in one launch (blockIdx.y selects)
__global__ __launch_bounds__(256) void cast4_kernel(
    const float* __restrict__ s0, const float* __restrict__ s1,
    const float* __restrict__ s2, const float* __restrict__ s3,
    bf16_t* __restrict__ d0, bf16_t* __restrict__ d1,
    bf16_t* __restrict__ d2, bf16_t* __restrict__ d3, int n4) {
    const int z = blockIdx.y;
    const float* src = (z == 0) ? s0 : (z == 1) ? s1 : (z == 2) ? s2 : s3;
    bf16_t* dst = (z == 0) ? d0 : (z == 1) ? d1 : (z == 2) ? d2 : d3;
    int i = blockIdx.x * 256 + threadIdx.x;
    if (i < n4) {
        const float4 v = ((const float4*)src)[i];
        bf16x4 o;
        o[0] = (bf16_t)v.x; o[1] = (bf16_t)v.y;
        o[2] = (bf16_t)v.z; o[3] = (bf16_t)v.w;
        ((bf16x4*)dst)[i] = o;
    }
}

// ---------------------------------------------------------------------------
// E (fp32, 2047x64) -> Eb (bf16, 2048x64) with a prepended zero row.
// rel[i,j] = q_i . E[j-i+L-2]; zero exactly at j-i = 1-L  =>  Eb[j-i+L-1]
// ---------------------------------------------------------------------------
__global__ __launch_bounds__(256) void conv_e_kernel(const float* __restrict__ E,
                                                     bf16_t* __restrict__ Eb) {
    int idx = blockIdx.x * 256 + threadIdx.x;
    if (idx < 64) Eb[idx] = (bf16_t)0.f;
    if (idx < 2047 * 64) Eb[64 + idx] = (bf16_t)E[idx];
}

// ---------------------------------------------------------------------------
// Fused QKV GEMM (unchanged from r8): blockIdx.z selects Q/K/V; V emitted
// transposed per-head (vtb[bh][d][j]).
// ---------------------------------------------------------------------------
__global__ __launch_bounds__(256) void qkv_gemm_kernel(
    const bf16_t* __restrict__ xb,
    const bf16_t* __restrict__ Wqb, const bf16_t* __restrict__ Wkb,
    const bf16_t* __restrict__ Wvb,
    const float* __restrict__ bq, const float* __restrict__ bk2,
    const float* __restrict__ bv2,
    bf16_t* __restrict__ qbh, bf16_t* __restrict__ kbh,
    bf16_t* __restrict__ vtb) {
    constexpr int K = D_;
    __shared__ __align__(16) bf16_t As[64][72];
    __shared__ __align__(16) bf16_t Bs[64][72];

    const int z = blockIdx.z;
    const bf16_t* W = (z == 0) ? Wqb : (z == 1) ? Wkb : Wvb;
    const float* bias = (z == 0) ? bq : (z == 1) ? bk2 : bv2;
    const float alpha = (z == 0) ? 0.125f : 1.0f;

    const int tid = threadIdx.x;
    const int m0 = blockIdx.y * 64;
    const int n0 = blockIdx.x * 64;
    const int wave = tid >> 6;
    const int lane = tid & 63;
    const int wm = (wave >> 1) << 5;
    const int wn = (wave & 1) << 5;
    const int lrow = lane & 15;
    const int quad = lane >> 4;
    const int r0 = tid >> 3;
    const int c8 = (tid & 7) << 3;

    f32x4 acc[2][2] = {};

    for (int k0 = 0; k0 < K; k0 += 64) {
        *(uint4*)&As[r0][c8]      = *(const uint4*)&xb[(size_t)(m0 + r0) * K + k0 + c8];
        *(uint4*)&As[r0 + 32][c8] = *(const uint4*)&xb[(size_t)(m0 + r0 + 32) * K + k0 + c8];
        *(uint4*)&Bs[r0][c8]      = *(const uint4*)&W[(size_t)(n0 + r0) * K + k0 + c8];
        *(uint4*)&Bs[r0 + 32][c8] = *(const uint4*)&W[(size_t)(n0 + r0 + 32) * K + k0 + c8];
        __syncthreads();

#pragma unroll
        for (int kc = 0; kc < 2; ++kc) {
            bf16x8 af[2], bfr[2];
            af[0]  = *(const bf16x8*)&As[wm + lrow][kc * 32 + 8 * quad];
            af[1]  = *(const bf16x8*)&As[wm + 16 + lrow][kc * 32 + 8 * quad];
            bfr[0] = *(const bf16x8*)&Bs[wn + lrow][kc * 32 + 8 * quad];
            bfr[1] = *(const bf16x8*)&Bs[wn + 16 + lrow][kc * 32 + 8 * quad];
#pragma unroll
            for (int t = 0; t < 2; ++t)
#pragma unroll
                for (int u = 0; u < 2; ++u)
                    acc[t][u] = __builtin_amdgcn_mfma_f32_16x16x32_bf16(
                        af[t], bfr[u], acc[t][u], 0, 0, 0);
        }
        __syncthreads();
    }

#pragma unroll
    for (int t = 0; t < 2; ++t) {
#pragma unroll
        for (int u = 0; u < 2; ++u) {
            const int col = n0 + wn + u * 16 + lrow;
            const float bvv = bias[col];
            const int h = col >> 6, d = col & 63;
            if (z < 2) {
                bf16_t* outp = z ? kbh : qbh;
#pragma unroll
                for (int r = 0; r < 4; ++r) {
                    const int row = m0 + wm + t * 16 + quad * 4 + r;
                    const int b = row >> 10, i = row & 1023;
                    outp[((size_t)((b * H_ + h) * L_ + i)) * HD_ + d] =
                        (bf16_t)((acc[t][u][r] + bvv) * alpha);
                }
            } else {
                const int row0 = m0 + wm + t * 16 + quad * 4;
                const int b = row0 >> 10, i = row0 & 1023;
                bf16x4 pk;
#pragma unroll
                for (int r = 0; r < 4; ++r) pk[r] = (bf16_t)(acc[t][u][r] + bvv);
                *(bf16x4*)&vtb[((size_t)((b * H_ + h) * HD_ + d)) * L_ + i] = pk;
            }
        }
    }
}

// ---------------------------------------------------------------------------
// Wo GEMM (unchanged from r8).
// ---------------------------------------------------------------------------
__global__ __launch_bounds__(256) void out_gemm_kernel(
    const bf16_t* __restrict__ A, const bf16_t* __restrict__ W,
    const float* __restrict__ bias, float* __restrict__ outF) {
    constexpr int K = D_;
    __shared__ __align__(16) bf16_t As[64][72];
    __shared__ __align__(16) bf16_t Bs[64][72];

    const int tid = threadIdx.x;
    const int m0 = blockIdx.y * 64;
    const int n0 = blockIdx.x * 64;
    const int wave = tid >> 6;
    const int lane = tid & 63;
    const int wm = (wave >> 1) << 5;
    const int wn = (wave & 1) << 5;
    const int lrow = lane & 15;
    const int quad = lane >> 4;
    const int r0 = tid >> 3;
    const int c8 = (tid & 7) << 3;

    f32x4 acc[2][2] = {};

    for (int k0 = 0; k0 < K; k0 += 64) {
        *(uint4*)&As[r0][c8]      = *(const uint4*)&A[(size_t)(m0 + r0) * K + k0 + c8];
        *(uint4*)&As[r0 + 32][c8] = *(const uint4*)&A[(size_t)(m0 + r0 + 32) * K + k0 + c8];
        *(uint4*)&Bs[r0][c8]      = *(const uint4*)&W[(size_t)(n0 + r0) * K + k0 + c8];
        *(uint4*)&Bs[r0 + 32][c8] = *(const uint4*)&W[(size_t)(n0 + r0 + 32) * K + k0 + c8];
        __syncthreads();

#pragma unroll
        for (int kc = 0; kc < 2; ++kc) {
            bf16x8 af[2], bfr[2];
            af[0]  = *(const bf16x8*)&As[wm + lrow][kc * 32 + 8 * quad];
            af[1]  = *(const bf16x8*)&As[wm + 16 + lrow][kc * 32 + 8 * quad];
            bfr[0] = *(const bf16x8*)&Bs[wn + lrow][kc * 32 + 8 * quad];
            bfr[1] = *(const bf16x8*)&Bs[wn + 16 + lrow][kc * 32 + 8 * quad];
#pragma unroll
            for (int t = 0; t < 2; ++t)
#pragma unroll
                for (int u = 0; u < 2; ++u)
                    acc[t][u] = __builtin_amdgcn_mfma_f32_16x16x32_bf16(
                        af[t], bfr[u], acc[t][u], 0, 0, 0);
        }
        __syncthreads();
    }

#pragma unroll
    for (int t = 0; t < 2; ++t) {
#pragma unroll
        for (int u = 0; u < 2; ++u) {
            const int col = n0 + wn + u * 16 + lrow;
            const float bvv = bias[col];
#pragma unroll
            for (int r = 0; r < 4; ++r) {
                const int row = m0 + wm + t * 16 + quad * 4 + r;
                outF[(size_t)row * D_ + col] = acc[t][u][r] + bvv;
            }
        }
    }
}

// ---------------------------------------------------------------------------
// MFMA flash attention, 32 Q-rows per wave (2 m-fragments), K-split 4.
// Every K/V/E fragment load feeds 2 MFMAs (reused across m) -> half the
// global transactions per output row vs r8. Barrier-free loop; fp32 4-way
// merge via LDS union at the end.
// ---------------------------------------------------------------------------
__global__ __launch_bounds__(256) void fattn_kernel(
    const bf16_t* __restrict__ qbh, const bf16_t* __restrict__ kbh,
    const bf16_t* __restrict__ vtb, const bf16_t* __restrict__ Eb,
    bf16_t* __restrict__ ctx) {
    // loop phase: RP[4][32][104] bf16 = 26624 B (wave-private R band / P tile)
    // merge phase: Om[4][32][64] f32 = 32768 B | ml[4][32][2] f32 = 1024 B
    __shared__ __align__(16) char smem[33792];
    bf16_t (*RP)[32][104] = (bf16_t(*)[32][104])smem;
    float  (*Om)[32][64]  = (float(*)[32][64])smem;
    float  (*ml)[32][2]   = (float(*)[32][2])(smem + 32768);

    const int tid = threadIdx.x;
    const int w = tid >> 6;          // wave = K-quarter
    const int lane = tid & 63;
    const int q4 = lane >> 4;
    const int n = lane & 15;
    const int bh = blockIdx.y;
    const int b = bh >> 4;
    const int h = bh & 15;
    const int ib = blockIdx.x * 32;  // Q-row base (shared by all 4 waves)

    // Q A-fragments: 2 groups of 16 rows, held all kernel.
    bf16x8 aq[2][2];
#pragma unroll
    for (int m = 0; m < 2; ++m) {
        const bf16x8* qrow =
            (const bf16x8*)(qbh + ((size_t)bh * L_ + ib + 16 * m + n) * HD_);
        aq[m][0] = qrow[q4];
        aq[m][1] = qrow[4 + q4];
    }

    const bf16_t* vbase = vtb + (size_t)bh * HD_ * L_;

    f32x4 o[2][4] = {};
    float m_r[2][4], l_r[2][4];
#pragma unroll
    for (int m = 0; m < 2; ++m)
#pragma unroll
        for (int r = 0; r < 4; ++r) { m_r[m][r] = -1e30f; l_r[m][r] = 0.f; }

    for (int t = 0; t < 4; ++t) {
        const int j0 = w * 256 + t * 64;

        // ---- S = Q K^T (K frags reused across both m groups) ----
        f32x4 s[2][4] = {};
#pragma unroll
        for (int u = 0; u < 4; ++u) {
#pragma unroll
            for (int kc = 0; kc < 2; ++kc) {
                const bf16x8 bk = *(const bf16x8*)(kbh +
                    ((size_t)bh * L_ + j0 + 16 * u + n) * HD_ + kc * 32 + 8 * q4);
#pragma unroll
                for (int m = 0; m < 2; ++m)
                    s[m][u] = __builtin_amdgcn_mfma_f32_16x16x32_bf16(
                        aq[m][kc], bk, s[m][u], 0, 0, 0);
            }
        }

        // ---- R = Q @ Eband^T: p = jj - row_local + 31 in [0,94], 6 tiles ----
        const int rbase = j0 - ib + 992;   // Eb row = rbase + p, in [0,2046]
#pragma unroll
        for (int up = 0; up < 6; ++up) {
            f32x4 rc[2] = {};
#pragma unroll
            for (int kc = 0; kc < 2; ++kc) {
                const bf16x8 be = *(const bf16x8*)(Eb +
                    ((size_t)(rbase + 16 * up + n)) * HD_ + kc * 32 + 8 * q4);
#pragma unroll
                for (int m = 0; m < 2; ++m)
                    rc[m] = __builtin_amdgcn_mfma_f32_16x16x32_bf16(
                        aq[m][kc], be, rc[m], 0, 0, 0);
            }
#pragma unroll
            for (int m = 0; m < 2; ++m)
#pragma unroll
                for (int r = 0; r < 4; ++r)
                    RP[w][16 * m + 4 * q4 + r][16 * up + n] = (bf16_t)rc[m][r];
        }

        // ---- skew add: S[row][jj] += R[row][jj - row + 31] ----
#pragma unroll
        for (int m = 0; m < 2; ++m)
#pragma unroll
            for (int u = 0; u < 4; ++u)
#pragma unroll
                for (int r = 0; r < 4; ++r) {
                    const int row = 16 * m + 4 * q4 + r;
                    s[m][u][r] += (float)RP[w][row][16 * u + n - row + 31];
                }

        // ---- online softmax (rows across 16-lane groups) ----
#pragma unroll
        for (int m = 0; m < 2; ++m) {
#pragma unroll
            for (int r = 0; r < 4; ++r) {
                float mt = fmaxf(fmaxf(s[m][0][r], s[m][1][r]),
                                 fmaxf(s[m][2][r], s[m][3][r]));
                mt = fmaxf(mt, __shfl_xor(mt, 1));
                mt = fmaxf(mt, __shfl_xor(mt, 2));
                mt = fmaxf(mt, __shfl_xor(mt, 4));
                mt = fmaxf(mt, __shfl_xor(mt, 8));
                const float mn = fmaxf(m_r[m][r], mt);
                const float al = __expf(m_r[m][r] - mn);
                m_r[m][r] = mn;
                float ps = 0.f;
#pragma unroll
                for (int u = 0; u < 4; ++u) {
                    const float pv = __expf(s[m][u][r] - mn);
                    s[m][u][r] = pv;
                    ps += pv;
                }
                ps += __shfl_xor(ps, 1);
                ps += __shfl_xor(ps, 2);
                ps += __shfl_xor(ps, 4);
                ps += __shfl_xor(ps, 8);
                l_r[m][r] = l_r[m][r] * al + ps;
#pragma unroll
                for (int u = 0; u < 4; ++u) o[m][u][r] *= al;
            }
        }

        // ---- P -> LDS (own-wave rows), then A-frags ----
#pragma unroll
        for (int m = 0; m < 2; ++m)
#pragma unroll
            for (int u = 0; u < 4; ++u)
#pragma unroll
                for (int r = 0; r < 4; ++r)
                    RP[w][16 * m + 4 * q4 + r][16 * u + n] = (bf16_t)s[m][u][r];

        bf16x8 pa[2][2];
#pragma unroll
        for (int m = 0; m < 2; ++m) {
            pa[m][0] = *(const bf16x8*)&RP[w][16 * m + n][8 * q4];
            pa[m][1] = *(const bf16x8*)&RP[w][16 * m + n][32 + 8 * q4];
        }

        // ---- O += P V (V frags reused across both m groups) ----
#pragma unroll
        for (int u = 0; u < 4; ++u) {
#pragma unroll
            for (int kc = 0; kc < 2; ++kc) {
                const bf16x8 bv = *(const bf16x8*)(vbase +
                    ((size_t)(16 * u + n)) * L_ + j0 + kc * 32 + 8 * q4);
#pragma unroll
                for (int m = 0; m < 2; ++m)
                    o[m][u] = __builtin_amdgcn_mfma_f32_16x16x32_bf16(
                        pa[m][kc], bv, o[m][u], 0, 0, 0);
            }
        }
    }

    // ---- 4-way cross-wave merge ----
    __syncthreads();   // all waves done with RP before Om alias writes
#pragma unroll
    for (int m = 0; m < 2; ++m)
#pragma unroll
        for (int u = 0; u < 4; ++u)
#pragma unroll
            for (int r = 0; r < 4; ++r)
                Om[w][16 * m + 4 * q4 + r][16 * u + n] = o[m][u][r];
    if (n == 0) {
#pragma unroll
        for (int m = 0; m < 2; ++m)
#pragma unroll
            for (int r = 0; r < 4; ++r) {
                ml[w][16 * m + 4 * q4 + r][0] = m_r[m][r];
                ml[w][16 * m + 4 * q4 + r][1] = l_r[m][r];
            }
    }
    __syncthreads();

    {
        const int row = tid >> 3;          // 0..31
        const int c0 = (tid & 7) * 8;      // 0..56
        const float m0v = ml[0][row][0], m1v = ml[1][row][0];
        const float m2v = ml[2][row][0], m3v = ml[3][row][0];
        const float ms = fmaxf(fmaxf(m0v, m1v), fmaxf(m2v, m3v));
        const float a0 = __expf(m0v - ms), a1 = __expf(m1v - ms);
        const float a2 = __expf(m2v - ms), a3 = __expf(m3v - ms);
        const float inv = 1.f / (a0 * ml[0][row][1] + a1 * ml[1][row][1] +
                                 a2 * ml[2][row][1] + a3 * ml[3][row][1]);
        bf16_t* dst = ctx + ((size_t)(b * L_ + ib + row)) * D_ + h * HD_ + c0;
#pragma unroll
        for (int cc = 0; cc < 8; ++cc) {
            const int col = c0 + cc;
            const float val = (a0 * Om[0][row][col] + a1 * Om[1][row][col] +
                               a2 * Om[2][row][col] + a3 * Om[3][row][col]) * inv;
            dst[cc] = (bf16_t)val;
        }
    }
}

// ---------------------------------------------------------------------------
extern "C" void kernel_launch(void* const* d_in, const int* in_sizes, int n_in,
                              void* d_out, int out_size, void* d_ws,
                              size_t ws_size, hipStream_t stream) {
    const float* x   = (const float*)d_in[0];
    const float* Wq  = (const float*)d_in[1];
    const float* bq  = (const float*)d_in[2];
    const float* Wk  = (const float*)d_in[3];
    const float* bk  = (const float*)d_in[4];
    const float* Wv  = (const float*)d_in[5];
    const float* bv  = (const float*)d_in[6];
    const float* Wo  = (const float*)d_in[7];
    const float* bo  = (const float*)d_in[8];
    const float* E   = (const float*)d_in[9];
    float* out = (float*)d_out;   // fp32 per reference (validated round 5)

    char* ws = (char*)d_ws;
    const size_t MB = 1024u * 1024u;
    bf16_t* xb   = (bf16_t*)(ws);             // 4 MB
    bf16_t* Wqb  = (bf16_t*)(ws + 4 * MB);    // 2 MB
    bf16_t* Wkb  = (bf16_t*)(ws + 6 * MB);    // 2 MB
    bf16_t* Wvb  = (bf16_t*)(ws + 8 * MB);    // 2 MB
    bf16_t* Wob  = (bf16_t*)(ws + 10 * MB);   // 2 MB
    bf16_t* qbh  = (bf16_t*)(ws + 12 * MB);   // 4 MB (BH,L,64), pre-scaled
    bf16_t* kbh  = (bf16_t*)(ws + 16 * MB);   // 4 MB (BH,L,64)
    bf16_t* vtb  = (bf16_t*)(ws + 20 * MB);   // 4 MB (BH,64,L) transposed
    bf16_t* ctxb = (bf16_t*)(ws + 24 * MB);   // 4 MB (B,L,D)
    bf16_t* Eb   = (bf16_t*)(ws + 28 * MB);   // 0.25 MB (2048x64)

    conv_e_kernel<<<512, 256, 0, stream>>>(E, Eb);
    cast_kernel<<<2048, 256, 0, stream>>>(x, xb, (B_ * L_ * D_) / 4);
    dim3 gc(1024, 4);
    cast4_kernel<<<gc, 256, 0, stream>>>(Wq, Wk, Wv, Wo, Wqb, Wkb, Wvb, Wob,
                                         (D_ * D_) / 4);

    dim3 gq(D_ / 64, (B_ * L_) / 64, 3);  // 1536 blocks
    qkv_gemm_kernel<<<gq, 256, 0, stream>>>(xb, Wqb, Wkb, Wvb, bq, bk, bv,
                                            qbh, kbh, vtb);

    dim3 ga(L_ / 32, B_ * H_);  // (32, 32) = 1024 blocks
    fattn_kernel<<<ga, 256, 0, stream>>>(qbh, kbh, vtb, Eb, ctxb);

    dim3 gg(D_ / 64, (B_ * L_) / 64);  // 512 blocks
    out_gemm_kernel<<<gg, 256, 0, stream>>>(ctxb, Wob, bo, out);
}

// Round 11
// 194.019 us; speedup vs baseline: 1.2875x; 1.0831x over previous
//
#include <hip/hip_runtime.h>
#include <hip/hip_bf16.h>

typedef __bf16 bf16_t;
typedef __bf16 bf16x8 __attribute__((ext_vector_type(8)));
typedef __bf16 bf16x4 __attribute__((ext_vector_type(4)));
typedef float f32x4 __attribute__((ext_vector_type(4)));

#define B_ 2
#define L_ 1024
#define D_ 1024
#define H_ 16
#define HD_ 64

// ---------------------------------------------------------------------------
// Fused prep: x-cast (blocks 0..2047), W casts (2048..6143), E shift+cast
// (6144..6655).
// ---------------------------------------------------------------------------
__global__ __launch_bounds__(256) void prep_kernel(
    const float* __restrict__ x,
    const float* __restrict__ Wq, const float* __restrict__ Wk,
    const float* __restrict__ Wv, const float* __restrict__ Wo,
    const float* __restrict__ E,
    bf16_t* __restrict__ xb,
    bf16_t* __restrict__ Wqb, bf16_t* __restrict__ Wkb,
    bf16_t* __restrict__ Wvb, bf16_t* __restrict__ Wob,
    bf16_t* __restrict__ Eb) {
    const int bid = blockIdx.x;
    if (bid < 6144) {
        const float* src;
        bf16_t* dst;
        int i;
        if (bid < 2048) {
            src = x; dst = xb; i = bid * 256 + threadIdx.x;
        } else {
            const int z = (bid - 2048) >> 10;
            src = (z == 0) ? Wq : (z == 1) ? Wk : (z == 2) ? Wv : Wo;
            dst = (z == 0) ? Wqb : (z == 1) ? Wkb : (z == 2) ? Wvb : Wob;
            i = ((bid - 2048) & 1023) * 256 + threadIdx.x;
        }
        const float4 v = ((const float4*)src)[i];
        bf16x4 o;
        o[0] = (bf16_t)v.x; o[1] = (bf16_t)v.y;
        o[2] = (bf16_t)v.z; o[3] = (bf16_t)v.w;
        ((bf16x4*)dst)[i] = o;
    } else {
        // Eb row 0 = zeros (r = -1 skew corner), rows 1..2047 = E cast.
        const int idx = (bid - 6144) * 256 + threadIdx.x;
        if (idx < 64) Eb[idx] = (bf16_t)0.f;
        if (idx < 2047 * 64) Eb[64 + idx] = (bf16_t)E[idx];
    }
}

// ---------------------------------------------------------------------------
// Fused QKV GEMM with register double-buffered staging.
// blockIdx.z selects Q/K/V; V emitted transposed per-head (vtb[bh][d][j]).
// ---------------------------------------------------------------------------
__global__ __launch_bounds__(256) void qkv_gemm_kernel(
    const bf16_t* __restrict__ xb,
    const bf16_t* __restrict__ Wqb, const bf16_t* __restrict__ Wkb,
    const bf16_t* __restrict__ Wvb,
    const float* __restrict__ bq, const float* __restrict__ bk2,
    const float* __restrict__ bv2,
    bf16_t* __restrict__ qbh, bf16_t* __restrict__ kbh,
    bf16_t* __restrict__ vtb) {
    constexpr int K = D_;
    __shared__ __align__(16) bf16_t As[64][72];
    __shared__ __align__(16) bf16_t Bs[64][72];

    const int z = blockIdx.z;
    const bf16_t* W = (z == 0) ? Wqb : (z == 1) ? Wkb : Wvb;
    const float* bias = (z == 0) ? bq : (z == 1) ? bk2 : bv2;
    const float alpha = (z == 0) ? 0.125f : 1.0f;

    const int tid = threadIdx.x;
    const int m0 = blockIdx.y * 64;
    const int n0 = blockIdx.x * 64;
    const int wave = tid >> 6;
    const int lane = tid & 63;
    const int wm = (wave >> 1) << 5;
    const int wn = (wave & 1) << 5;
    const int lrow = lane & 15;
    const int quad = lane >> 4;
    const int r0 = tid >> 3;
    const int c8 = (tid & 7) << 3;

    f32x4 acc[2][2] = {};

    uint4 pA0 = *(const uint4*)&xb[(size_t)(m0 + r0) * K + c8];
    uint4 pA1 = *(const uint4*)&xb[(size_t)(m0 + r0 + 32) * K + c8];
    uint4 pB0 = *(const uint4*)&W[(size_t)(n0 + r0) * K + c8];
    uint4 pB1 = *(const uint4*)&W[(size_t)(n0 + r0 + 32) * K + c8];

    for (int k0 = 0; k0 < K; k0 += 64) {
        *(uint4*)&As[r0][c8] = pA0;
        *(uint4*)&As[r0 + 32][c8] = pA1;
        *(uint4*)&Bs[r0][c8] = pB0;
        *(uint4*)&Bs[r0 + 32][c8] = pB1;
        const int kn = (k0 + 64 < K) ? k0 + 64 : k0;
        pA0 = *(const uint4*)&xb[(size_t)(m0 + r0) * K + kn + c8];
        pA1 = *(const uint4*)&xb[(size_t)(m0 + r0 + 32) * K + kn + c8];
        pB0 = *(const uint4*)&W[(size_t)(n0 + r0) * K + kn + c8];
        pB1 = *(const uint4*)&W[(size_t)(n0 + r0 + 32) * K + kn + c8];
        __syncthreads();

#pragma unroll
        for (int kc = 0; kc < 2; ++kc) {
            bf16x8 af[2], bfr[2];
            af[0]  = *(const bf16x8*)&As[wm + lrow][kc * 32 + 8 * quad];
            af[1]  = *(const bf16x8*)&As[wm + 16 + lrow][kc * 32 + 8 * quad];
            bfr[0] = *(const bf16x8*)&Bs[wn + lrow][kc * 32 + 8 * quad];
            bfr[1] = *(const bf16x8*)&Bs[wn + 16 + lrow][kc * 32 + 8 * quad];
#pragma unroll
            for (int t = 0; t < 2; ++t)
#pragma unroll
                for (int u = 0; u < 2; ++u)
                    acc[t][u] = __builtin_amdgcn_mfma_f32_16x16x32_bf16(
                        af[t], bfr[u], acc[t][u], 0, 0, 0);
        }
        __syncthreads();
    }

#pragma unroll
    for (int t = 0; t < 2; ++t) {
#pragma unroll
        for (int u = 0; u < 2; ++u) {
            const int col = n0 + wn + u * 16 + lrow;
            const float bvv = bias[col];
            const int h = col >> 6, d = col & 63;
            if (z < 2) {
                bf16_t* outp = z ? kbh : qbh;
#pragma unroll
                for (int r = 0; r < 4; ++r) {
                    const int row = m0 + wm + t * 16 + quad * 4 + r;
                    const int b = row >> 10, i = row & 1023;
                    outp[((size_t)((b * H_ + h) * L_ + i)) * HD_ + d] =
                        (bf16_t)((acc[t][u][r] + bvv) * alpha);
                }
            } else {
                const int row0 = m0 + wm + t * 16 + quad * 4;
                const int b = row0 >> 10, i = row0 & 1023;
                bf16x4 pk;
#pragma unroll
                for (int r = 0; r < 4; ++r) pk[r] = (bf16_t)(acc[t][u][r] + bvv);
                *(bf16x4*)&vtb[((size_t)((b * H_ + h) * HD_ + d)) * L_ + i] = pk;
            }
        }
    }
}

// ---------------------------------------------------------------------------
// Wo GEMM with register double-buffered staging, fp32 out.
// ---------------------------------------------------------------------------
__global__ __launch_bounds__(256) void out_gemm_kernel(
    const bf16_t* __restrict__ A, const bf16_t* __restrict__ W,
    const float* __restrict__ bias, float* __restrict__ outF) {
    constexpr int K = D_;
    __shared__ __align__(16) bf16_t As[64][72];
    __shared__ __align__(16) bf16_t Bs[64][72];

    const int tid = threadIdx.x;
    const int m0 = blockIdx.y * 64;
    const int n0 = blockIdx.x * 64;
    const int wave = tid >> 6;
    const int lane = tid & 63;
    const int wm = (wave >> 1) << 5;
    const int wn = (wave & 1) << 5;
    const int lrow = lane & 15;
    const int quad = lane >> 4;
    const int r0 = tid >> 3;
    const int c8 = (tid & 7) << 3;

    f32x4 acc[2][2] = {};

    uint4 pA0 = *(const uint4*)&A[(size_t)(m0 + r0) * K + c8];
    uint4 pA1 = *(const uint4*)&A[(size_t)(m0 + r0 + 32) * K + c8];
    uint4 pB0 = *(const uint4*)&W[(size_t)(n0 + r0) * K + c8];
    uint4 pB1 = *(const uint4*)&W[(size_t)(n0 + r0 + 32) * K + c8];

    for (int k0 = 0; k0 < K; k0 += 64) {
        *(uint4*)&As[r0][c8] = pA0;
        *(uint4*)&As[r0 + 32][c8] = pA1;
        *(uint4*)&Bs[r0][c8] = pB0;
        *(uint4*)&Bs[r0 + 32][c8] = pB1;
        const int kn = (k0 + 64 < K) ? k0 + 64 : k0;
        pA0 = *(const uint4*)&A[(size_t)(m0 + r0) * K + kn + c8];
        pA1 = *(const uint4*)&A[(size_t)(m0 + r0 + 32) * K + kn + c8];
        pB0 = *(const uint4*)&W[(size_t)(n0 + r0) * K + kn + c8];
        pB1 = *(const uint4*)&W[(size_t)(n0 + r0 + 32) * K + kn + c8];
        __syncthreads();

#pragma unroll
        for (int kc = 0; kc < 2; ++kc) {
            bf16x8 af[2], bfr[2];
            af[0]  = *(const bf16x8*)&As[wm + lrow][kc * 32 + 8 * quad];
            af[1]  = *(const bf16x8*)&As[wm + 16 + lrow][kc * 32 + 8 * quad];
            bfr[0] = *(const bf16x8*)&Bs[wn + lrow][kc * 32 + 8 * quad];
            bfr[1] = *(const bf16x8*)&Bs[wn + 16 + lrow][kc * 32 + 8 * quad];
#pragma unroll
            for (int t = 0; t < 2; ++t)
#pragma unroll
                for (int u = 0; u < 2; ++u)
                    acc[t][u] = __builtin_amdgcn_mfma_f32_16x16x32_bf16(
                        af[t], bfr[u], acc[t][u], 0, 0, 0);
        }
        __syncthreads();
    }

#pragma unroll
    for (int t = 0; t < 2; ++t) {
#pragma unroll
        for (int u = 0; u < 2; ++u) {
            const int col = n0 + wn + u * 16 + lrow;
            const float bvv = bias[col];
#pragma unroll
            for (int r = 0; r < 4; ++r) {
                const int row = m0 + wm + t * 16 + quad * 4 + r;
                outF[(size_t)row * D_ + col] = acc[t][u][r] + bvv;
            }
        }
    }
}

// ---------------------------------------------------------------------------
// MFMA flash attention, 32 Q-rows/wave, K-split 4, software-pipelined iter.
// FIX vs r10: P tile stride 40 -> 72 (64 cols + pad) and P aliases the band
// buffer (band is dead after skew-add; same-wave LDS ops are in-order), so
// LDS stays 33792 B.
// ---------------------------------------------------------------------------
__global__ __launch_bounds__(256) void fattn_kernel(
    const bf16_t* __restrict__ qbh, const bf16_t* __restrict__ kbh,
    const bf16_t* __restrict__ vtb, const bf16_t* __restrict__ Eb,
    bf16_t* __restrict__ ctx) {
    // loop phase : band[w] = [96][36] bf16 @ w*6912 (27648 B total);
    //              P tile reuses band[w] with stride 72 (needs 2304 el < 3456)
    // merge phase: Om[4][32][64] f32 @ 0 | ml[4][32][2] f32 @ 32768
    __shared__ __align__(16) char smem[33792];
    float (*Om)[32][64] = (float(*)[32][64])smem;
    float (*ml)[32][2]  = (float(*)[32][2])(smem + 32768);

    const int tid = threadIdx.x;
    const int w = tid >> 6;
    const int lane = tid & 63;
    const int q4 = lane >> 4;
    const int n = lane & 15;
    const int bh = blockIdx.y;
    const int b = bh >> 4;
    const int h = bh & 15;
    const int ib = blockIdx.x * 32;

    bf16_t* band = (bf16_t*)smem + (size_t)w * (96 * 36);
    bf16_t* ps = band;   // aliased: band dead after skew-add, P stride 72

    // Q A-fragments: 2 groups of 16 rows, held all kernel.
    bf16x8 aq[2][2];
#pragma unroll
    for (int m = 0; m < 2; ++m) {
        const bf16x8* qrow =
            (const bf16x8*)(qbh + ((size_t)bh * L_ + ib + 16 * m + n) * HD_);
        aq[m][0] = qrow[q4];
        aq[m][1] = qrow[4 + q4];
    }

    const bf16_t* vbase = vtb + (size_t)bh * HD_ * L_;

    f32x4 o[2][4] = {};
    float m_r[2][4], l_r[2][4];
#pragma unroll
    for (int m = 0; m < 2; ++m)
#pragma unroll
        for (int r = 0; r < 4; ++r) { m_r[m][r] = -1e30f; l_r[m][r] = 0.f; }

    for (int t = 0; t < 4; ++t) {
        const int j0 = w * 256 + t * 64;

        // ---- prefetch K fragments (latency hidden behind rel section) ----
        bf16x8 bk[4][2];
#pragma unroll
        for (int u = 0; u < 4; ++u)
#pragma unroll
            for (int kc = 0; kc < 2; ++kc)
                bk[u][kc] = *(const bf16x8*)(kbh +
                    ((size_t)bh * L_ + j0 + 16 * u + n) * HD_ + kc * 32 + 8 * q4);

        // ---- rel: R = Q @ Eband^T, stored transposed band[p][row] ----
        const int rbase = j0 - ib + 992;   // Eb row = rbase + p, p in [0,95]
#pragma unroll
        for (int up = 0; up < 6; ++up) {
            f32x4 rc[2] = {};
#pragma unroll
            for (int kc = 0; kc < 2; ++kc) {
                const bf16x8 be = *(const bf16x8*)(Eb +
                    ((size_t)(rbase + 16 * up + n)) * HD_ + kc * 32 + 8 * q4);
#pragma unroll
                for (int m = 0; m < 2; ++m)
                    rc[m] = __builtin_amdgcn_mfma_f32_16x16x32_bf16(
                        aq[m][kc], be, rc[m], 0, 0, 0);
            }
#pragma unroll
            for (int m = 0; m < 2; ++m) {
                bf16x4 pk;
#pragma unroll
                for (int r = 0; r < 4; ++r) pk[r] = (bf16_t)rc[m][r];
                *(bf16x4*)&band[(size_t)(16 * up + n) * 36 + 16 * m + 4 * q4] = pk;
            }
        }

        // ---- S = Q K^T (bk already resident) ----
        f32x4 s[2][4] = {};
#pragma unroll
        for (int u = 0; u < 4; ++u)
#pragma unroll
            for (int kc = 0; kc < 2; ++kc)
#pragma unroll
                for (int m = 0; m < 2; ++m)
                    s[m][u] = __builtin_amdgcn_mfma_f32_16x16x32_bf16(
                        aq[m][kc], bk[u][kc], s[m][u], 0, 0, 0);

        // ---- prefetch V fragments (latency hidden behind softmax) ----
        bf16x8 vf[4][2];
#pragma unroll
        for (int u = 0; u < 4; ++u)
#pragma unroll
            for (int kc = 0; kc < 2; ++kc)
                vf[u][kc] = *(const bf16x8*)(vbase +
                    ((size_t)(16 * u + n)) * L_ + j0 + kc * 32 + 8 * q4);

        // ---- skew add: S[row][jj] += band[jj - row + 31][row] ----
#pragma unroll
        for (int m = 0; m < 2; ++m)
#pragma unroll
            for (int u = 0; u < 4; ++u)
#pragma unroll
                for (int r = 0; r < 4; ++r) {
                    const int row = 16 * m + 4 * q4 + r;
                    s[m][u][r] +=
                        (float)band[(size_t)(16 * u + n - row + 31) * 36 + row];
                }

        // ---- online softmax ----
#pragma unroll
        for (int m = 0; m < 2; ++m) {
#pragma unroll
            for (int r = 0; r < 4; ++r) {
                float mt = fmaxf(fmaxf(s[m][0][r], s[m][1][r]),
                                 fmaxf(s[m][2][r], s[m][3][r]));
                mt = fmaxf(mt, __shfl_xor(mt, 1));
                mt = fmaxf(mt, __shfl_xor(mt, 2));
                mt = fmaxf(mt, __shfl_xor(mt, 4));
                mt = fmaxf(mt, __shfl_xor(mt, 8));
                const float mn = fmaxf(m_r[m][r], mt);
                const float al = __expf(m_r[m][r] - mn);
                m_r[m][r] = mn;
                float psum = 0.f;
#pragma unroll
                for (int u = 0; u < 4; ++u) {
                    const float pv = __expf(s[m][u][r] - mn);
                    s[m][u][r] = pv;
                    psum += pv;
                }
                psum += __shfl_xor(psum, 1);
                psum += __shfl_xor(psum, 2);
                psum += __shfl_xor(psum, 4);
                psum += __shfl_xor(psum, 8);
                l_r[m][r] = l_r[m][r] * al + psum;
#pragma unroll
                for (int u = 0; u < 4; ++u) o[m][u][r] *= al;
            }
        }

        // ---- P -> LDS (stride 72, aliases dead band), then A-frags ----
#pragma unroll
        for (int m = 0; m < 2; ++m)
#pragma unroll
            for (int u = 0; u < 4; ++u)
#pragma unroll
                for (int r = 0; r < 4; ++r)
                    ps[(size_t)(16 * m + 4 * q4 + r) * 72 + 16 * u + n] =
                        (bf16_t)s[m][u][r];

        bf16x8 pa[2][2];
#pragma unroll
        for (int m = 0; m < 2; ++m) {
            pa[m][0] = *(const bf16x8*)&ps[(size_t)(16 * m + n) * 72 + 8 * q4];
            pa[m][1] = *(const bf16x8*)&ps[(size_t)(16 * m + n) * 72 + 32 + 8 * q4];
        }

        // ---- O += P V (vf already resident) ----
#pragma unroll
        for (int u = 0; u < 4; ++u)
#pragma unroll
            for (int kc = 0; kc < 2; ++kc)
#pragma unroll
                for (int m = 0; m < 2; ++m)
                    o[m][u] = __builtin_amdgcn_mfma_f32_16x16x32_bf16(
                        pa[m][kc], vf[u][kc], o[m][u], 0, 0, 0);
    }

    // ---- 4-way cross-wave merge (LDS aliased after barrier) ----
    __syncthreads();
#pragma unroll
    for (int m = 0; m < 2; ++m)
#pragma unroll
        for (int u = 0; u < 4; ++u)
#pragma unroll
            for (int r = 0; r < 4; ++r)
                Om[w][16 * m + 4 * q4 + r][16 * u + n] = o[m][u][r];
    if (n == 0) {
#pragma unroll
        for (int m = 0; m < 2; ++m)
#pragma unroll
            for (int r = 0; r < 4; ++r) {
                ml[w][16 * m + 4 * q4 + r][0] = m_r[m][r];
                ml[w][16 * m + 4 * q4 + r][1] = l_r[m][r];
            }
    }
    __syncthreads();

    {
        const int row = tid >> 3;          // 0..31
        const int c0 = (tid & 7) * 8;      // 0..56
        const float m0v = ml[0][row][0], m1v = ml[1][row][0];
        const float m2v = ml[2][row][0], m3v = ml[3][row][0];
        const float ms = fmaxf(fmaxf(m0v, m1v), fmaxf(m2v, m3v));
        const float a0 = __expf(m0v - ms), a1 = __expf(m1v - ms);
        const float a2 = __expf(m2v - ms), a3 = __expf(m3v - ms);
        const float inv = 1.f / (a0 * ml[0][row][1] + a1 * ml[1][row][1] +
                                 a2 * ml[2][row][1] + a3 * ml[3][row][1]);
        bf16_t* dst = ctx + ((size_t)(b * L_ + ib + row)) * D_ + h * HD_ + c0;
#pragma unroll
        for (int cc = 0; cc < 8; ++cc) {
            const int col = c0 + cc;
            const float val = (a0 * Om[0][row][col] + a1 * Om[1][row][col] +
                               a2 * Om[2][row][col] + a3 * Om[3][row][col]) * inv;
            dst[cc] = (bf16_t)val;
        }
    }
}

// ---------------------------------------------------------------------------
extern "C" void kernel_launch(void* const* d_in, const int* in_sizes, int n_in,
                              void* d_out, int out_size, void* d_ws,
                              size_t ws_size, hipStream_t stream) {
    const float* x   = (const float*)d_in[0];
    const float* Wq  = (const float*)d_in[1];
    const float* bq  = (const float*)d_in[2];
    const float* Wk  = (const float*)d_in[3];
    const float* bk  = (const float*)d_in[4];
    const float* Wv  = (const float*)d_in[5];
    const float* bv  = (const float*)d_in[6];
    const float* Wo  = (const float*)d_in[7];
    const float* bo  = (const float*)d_in[8];
    const float* E   = (const float*)d_in[9];
    float* out = (float*)d_out;   // fp32 per reference (validated round 5)

    char* ws = (char*)d_ws;
    const size_t MB = 1024u * 1024u;
    bf16_t* xb   = (bf16_t*)(ws);             // 4 MB
    bf16_t* Wqb  = (bf16_t*)(ws + 4 * MB);    // 2 MB
    bf16_t* Wkb  = (bf16_t*)(ws + 6 * MB);    // 2 MB
    bf16_t* Wvb  = (bf16_t*)(ws + 8 * MB);    // 2 MB
    bf16_t* Wob  = (bf16_t*)(ws + 10 * MB);   // 2 MB
    bf16_t* qbh  = (bf16_t*)(ws + 12 * MB);   // 4 MB (BH,L,64), pre-scaled
    bf16_t* kbh  = (bf16_t*)(ws + 16 * MB);   // 4 MB (BH,L,64)
    bf16_t* vtb  = (bf16_t*)(ws + 20 * MB);   // 4 MB (BH,64,L) transposed
    bf16_t* ctxb = (bf16_t*)(ws + 24 * MB);   // 4 MB (B,L,D)
    bf16_t* Eb   = (bf16_t*)(ws + 28 * MB);   // 0.25 MB (2048x64)

    prep_kernel<<<6656, 256, 0, stream>>>(x, Wq, Wk, Wv, Wo, E,
                                          xb, Wqb, Wkb, Wvb, Wob, Eb);

    dim3 gq(D_ / 64, (B_ * L_) / 64, 3);  // 1536 blocks
    qkv_gemm_kernel<<<gq, 256, 0, stream>>>(xb, Wqb, Wkb, Wvb, bq, bk, bv,
                                            qbh, kbh, vtb);

    dim3 ga(L_ / 32, B_ * H_);  // 1024 blocks
    fattn_kernel<<<ga, 256, 0, stream>>>(qbh, kbh, vtb, Eb, ctxb);

    dim3 gg(D_ / 64, (B_ * L_) / 64);  // 512 blocks
    out_gemm_kernel<<<gg, 256, 0, stream>>>(ctxb, Wob, bo, out);
}

// Round 12
// 184.413 us; speedup vs baseline: 1.3545x; 1.0521x over previous
//
#include <hip/hip_runtime.h>
#include <hip/hip_bf16.h>

typedef __bf16 bf16_t;
typedef __bf16 bf16x8 __attribute__((ext_vector_type(8)));
typedef __bf16 bf16x4 __attribute__((ext_vector_type(4)));
typedef float f32x4 __attribute__((ext_vector_type(4)));

#define B_ 2
#define L_ 1024
#define D_ 1024
#define H_ 16
#define HD_ 64

// DPP rotate-reduce helper: fmax with lane (i+N)%16 within each 16-lane row.
// row_ror:N ctrl = 0x120 | N. VALU-pipe cross-lane (no DS op).
template <int CTRL>
static __device__ __forceinline__ float dpp_fmax(float v) {
    const int t = __builtin_amdgcn_update_dpp(0, __float_as_int(v), CTRL,
                                              0xF, 0xF, true);
    return fmaxf(v, __int_as_float(t));
}

// ---------------------------------------------------------------------------
// Fused prep: x-cast (blocks 0..2047), W casts (2048..6143), E shift+cast
// (6144..6655).
// ---------------------------------------------------------------------------
__global__ __launch_bounds__(256) void prep_kernel(
    const float* __restrict__ x,
    const float* __restrict__ Wq, const float* __restrict__ Wk,
    const float* __restrict__ Wv, const float* __restrict__ Wo,
    const float* __restrict__ E,
    bf16_t* __restrict__ xb,
    bf16_t* __restrict__ Wqb, bf16_t* __restrict__ Wkb,
    bf16_t* __restrict__ Wvb, bf16_t* __restrict__ Wob,
    bf16_t* __restrict__ Eb) {
    const int bid = blockIdx.x;
    if (bid < 6144) {
        const float* src;
        bf16_t* dst;
        int i;
        if (bid < 2048) {
            src = x; dst = xb; i = bid * 256 + threadIdx.x;
        } else {
            const int z = (bid - 2048) >> 10;
            src = (z == 0) ? Wq : (z == 1) ? Wk : (z == 2) ? Wv : Wo;
            dst = (z == 0) ? Wqb : (z == 1) ? Wkb : (z == 2) ? Wvb : Wob;
            i = ((bid - 2048) & 1023) * 256 + threadIdx.x;
        }
        const float4 v = ((const float4*)src)[i];
        bf16x4 o;
        o[0] = (bf16_t)v.x; o[1] = (bf16_t)v.y;
        o[2] = (bf16_t)v.z; o[3] = (bf16_t)v.w;
        ((bf16x4*)dst)[i] = o;
    } else {
        const int idx = (bid - 6144) * 256 + threadIdx.x;
        if (idx < 64) Eb[idx] = (bf16_t)0.f;
        if (idx < 2047 * 64) Eb[64 + idx] = (bf16_t)E[idx];
    }
}

// ---------------------------------------------------------------------------
// Fused QKV GEMM with register double-buffered staging (r11, passing).
// ---------------------------------------------------------------------------
__global__ __launch_bounds__(256) void qkv_gemm_kernel(
    const bf16_t* __restrict__ xb,
    const bf16_t* __restrict__ Wqb, const bf16_t* __restrict__ Wkb,
    const bf16_t* __restrict__ Wvb,
    const float* __restrict__ bq, const float* __restrict__ bk2,
    const float* __restrict__ bv2,
    bf16_t* __restrict__ qbh, bf16_t* __restrict__ kbh,
    bf16_t* __restrict__ vtb) {
    constexpr int K = D_;
    __shared__ __align__(16) bf16_t As[64][72];
    __shared__ __align__(16) bf16_t Bs[64][72];

    const int z = blockIdx.z;
    const bf16_t* W = (z == 0) ? Wqb : (z == 1) ? Wkb : Wvb;
    const float* bias = (z == 0) ? bq : (z == 1) ? bk2 : bv2;
    const float alpha = (z == 0) ? 0.125f : 1.0f;

    const int tid = threadIdx.x;
    const int m0 = blockIdx.y * 64;
    const int n0 = blockIdx.x * 64;
    const int wave = tid >> 6;
    const int lane = tid & 63;
    const int wm = (wave >> 1) << 5;
    const int wn = (wave & 1) << 5;
    const int lrow = lane & 15;
    const int quad = lane >> 4;
    const int r0 = tid >> 3;
    const int c8 = (tid & 7) << 3;

    f32x4 acc[2][2] = {};

    uint4 pA0 = *(const uint4*)&xb[(size_t)(m0 + r0) * K + c8];
    uint4 pA1 = *(const uint4*)&xb[(size_t)(m0 + r0 + 32) * K + c8];
    uint4 pB0 = *(const uint4*)&W[(size_t)(n0 + r0) * K + c8];
    uint4 pB1 = *(const uint4*)&W[(size_t)(n0 + r0 + 32) * K + c8];

    for (int k0 = 0; k0 < K; k0 += 64) {
        *(uint4*)&As[r0][c8] = pA0;
        *(uint4*)&As[r0 + 32][c8] = pA1;
        *(uint4*)&Bs[r0][c8] = pB0;
        *(uint4*)&Bs[r0 + 32][c8] = pB1;
        const int kn = (k0 + 64 < K) ? k0 + 64 : k0;
        pA0 = *(const uint4*)&xb[(size_t)(m0 + r0) * K + kn + c8];
        pA1 = *(const uint4*)&xb[(size_t)(m0 + r0 + 32) * K + kn + c8];
        pB0 = *(const uint4*)&W[(size_t)(n0 + r0) * K + kn + c8];
        pB1 = *(const uint4*)&W[(size_t)(n0 + r0 + 32) * K + kn + c8];
        __syncthreads();

#pragma unroll
        for (int kc = 0; kc < 2; ++kc) {
            bf16x8 af[2], bfr[2];
            af[0]  = *(const bf16x8*)&As[wm + lrow][kc * 32 + 8 * quad];
            af[1]  = *(const bf16x8*)&As[wm + 16 + lrow][kc * 32 + 8 * quad];
            bfr[0] = *(const bf16x8*)&Bs[wn + lrow][kc * 32 + 8 * quad];
            bfr[1] = *(const bf16x8*)&Bs[wn + 16 + lrow][kc * 32 + 8 * quad];
#pragma unroll
            for (int t = 0; t < 2; ++t)
#pragma unroll
                for (int u = 0; u < 2; ++u)
                    acc[t][u] = __builtin_amdgcn_mfma_f32_16x16x32_bf16(
                        af[t], bfr[u], acc[t][u], 0, 0, 0);
        }
        __syncthreads();
    }

#pragma unroll
    for (int t = 0; t < 2; ++t) {
#pragma unroll
        for (int u = 0; u < 2; ++u) {
            const int col = n0 + wn + u * 16 + lrow;
            const float bvv = bias[col];
            const int h = col >> 6, d = col & 63;
            if (z < 2) {
                bf16_t* outp = z ? kbh : qbh;
#pragma unroll
                for (int r = 0; r < 4; ++r) {
                    const int row = m0 + wm + t * 16 + quad * 4 + r;
                    const int b = row >> 10, i = row & 1023;
                    outp[((size_t)((b * H_ + h) * L_ + i)) * HD_ + d] =
                        (bf16_t)((acc[t][u][r] + bvv) * alpha);
                }
            } else {
                const int row0 = m0 + wm + t * 16 + quad * 4;
                const int b = row0 >> 10, i = row0 & 1023;
                bf16x4 pk;
#pragma unroll
                for (int r = 0; r < 4; ++r) pk[r] = (bf16_t)(acc[t][u][r] + bvv);
                *(bf16x4*)&vtb[((size_t)((b * H_ + h) * HD_ + d)) * L_ + i] = pk;
            }
        }
    }
}

// ---------------------------------------------------------------------------
// Wo GEMM with register double-buffered staging, fp32 out (r11, passing).
// ---------------------------------------------------------------------------
__global__ __launch_bounds__(256) void out_gemm_kernel(
    const bf16_t* __restrict__ A, const bf16_t* __restrict__ W,
    const float* __restrict__ bias, float* __restrict__ outF) {
    constexpr int K = D_;
    __shared__ __align__(16) bf16_t As[64][72];
    __shared__ __align__(16) bf16_t Bs[64][72];

    const int tid = threadIdx.x;
    const int m0 = blockIdx.y * 64;
    const int n0 = blockIdx.x * 64;
    const int wave = tid >> 6;
    const int lane = tid & 63;
    const int wm = (wave >> 1) << 5;
    const int wn = (wave & 1) << 5;
    const int lrow = lane & 15;
    const int quad = lane >> 4;
    const int r0 = tid >> 3;
    const int c8 = (tid & 7) << 3;

    f32x4 acc[2][2] = {};

    uint4 pA0 = *(const uint4*)&A[(size_t)(m0 + r0) * K + c8];
    uint4 pA1 = *(const uint4*)&A[(size_t)(m0 + r0 + 32) * K + c8];
    uint4 pB0 = *(const uint4*)&W[(size_t)(n0 + r0) * K + c8];
    uint4 pB1 = *(const uint4*)&W[(size_t)(n0 + r0 + 32) * K + c8];

    for (int k0 = 0; k0 < K; k0 += 64) {
        *(uint4*)&As[r0][c8] = pA0;
        *(uint4*)&As[r0 + 32][c8] = pA1;
        *(uint4*)&Bs[r0][c8] = pB0;
        *(uint4*)&Bs[r0 + 32][c8] = pB1;
        const int kn = (k0 + 64 < K) ? k0 + 64 : k0;
        pA0 = *(const uint4*)&A[(size_t)(m0 + r0) * K + kn + c8];
        pA1 = *(const uint4*)&A[(size_t)(m0 + r0 + 32) * K + kn + c8];
        pB0 = *(const uint4*)&W[(size_t)(n0 + r0) * K + kn + c8];
        pB1 = *(const uint4*)&W[(size_t)(n0 + r0 + 32) * K + kn + c8];
        __syncthreads();

#pragma unroll
        for (int kc = 0; kc < 2; ++kc) {
            bf16x8 af[2], bfr[2];
            af[0]  = *(const bf16x8*)&As[wm + lrow][kc * 32 + 8 * quad];
            af[1]  = *(const bf16x8*)&As[wm + 16 + lrow][kc * 32 + 8 * quad];
            bfr[0] = *(const bf16x8*)&Bs[wn + lrow][kc * 32 + 8 * quad];
            bfr[1] = *(const bf16x8*)&Bs[wn + 16 + lrow][kc * 32 + 8 * quad];
#pragma unroll
            for (int t = 0; t < 2; ++t)
#pragma unroll
                for (int u = 0; u < 2; ++u)
                    acc[t][u] = __builtin_amdgcn_mfma_f32_16x16x32_bf16(
                        af[t], bfr[u], acc[t][u], 0, 0, 0);
        }
        __syncthreads();
    }

#pragma unroll
    for (int t = 0; t < 2; ++t) {
#pragma unroll
        for (int u = 0; u < 2; ++u) {
            const int col = n0 + wn + u * 16 + lrow;
            const float bvv = bias[col];
#pragma unroll
            for (int r = 0; r < 4; ++r) {
                const int row = m0 + wm + t * 16 + quad * 4 + r;
                outF[(size_t)row * D_ + col] = acc[t][u][r] + bvv;
            }
        }
    }
}

// ---------------------------------------------------------------------------
// MFMA flash attention. r12: softmax reductions off the DS pipe —
//   max via DPP row_ror (VALU), sum via MFMA P@ones (matrix pipe).
// Band stride 36 -> 40 (2-way/free bank pattern on b64 writes).
// DS ops/iter: 144 -> 80.
// ---------------------------------------------------------------------------
__global__ __launch_bounds__(256) void fattn_kernel(
    const bf16_t* __restrict__ qbh, const bf16_t* __restrict__ kbh,
    const bf16_t* __restrict__ vtb, const bf16_t* __restrict__ Eb,
    bf16_t* __restrict__ ctx) {
    // loop phase : band[w] = [96][40] bf16 @ w*7680 (30720 B total);
    //              P tile reuses band[w] with stride 72 (2304 el < 3840)
    // merge phase: Om[4][32][64] f32 @ 0 | ml[4][32][2] f32 @ 32768
    __shared__ __align__(16) char smem[33792];
    float (*Om)[32][64] = (float(*)[32][64])smem;
    float (*ml)[32][2]  = (float(*)[32][2])(smem + 32768);

    const int tid = threadIdx.x;
    const int w = tid >> 6;
    const int lane = tid & 63;
    const int q4 = lane >> 4;
    const int n = lane & 15;
    const int bh = blockIdx.y;
    const int b = bh >> 4;
    const int h = bh & 15;
    const int ib = blockIdx.x * 32;

    bf16_t* band = (bf16_t*)smem + (size_t)w * (96 * 40);
    bf16_t* ps = band;   // aliased: band dead after skew-add, P stride 72

    // ones B-fragment for the MFMA row-sum trick
    bf16x8 ones;
#pragma unroll
    for (int e = 0; e < 8; ++e) ones[e] = (bf16_t)1.0f;

    bf16x8 aq[2][2];
#pragma unroll
    for (int m = 0; m < 2; ++m) {
        const bf16x8* qrow =
            (const bf16x8*)(qbh + ((size_t)bh * L_ + ib + 16 * m + n) * HD_);
        aq[m][0] = qrow[q4];
        aq[m][1] = qrow[4 + q4];
    }

    const bf16_t* vbase = vtb + (size_t)bh * HD_ * L_;

    f32x4 o[2][4] = {};
    float m_r[2][4], l_r[2][4];
#pragma unroll
    for (int m = 0; m < 2; ++m)
#pragma unroll
        for (int r = 0; r < 4; ++r) { m_r[m][r] = -1e30f; l_r[m][r] = 0.f; }

    for (int t = 0; t < 4; ++t) {
        const int j0 = w * 256 + t * 64;

        // ---- prefetch K fragments ----
        bf16x8 bk[4][2];
#pragma unroll
        for (int u = 0; u < 4; ++u)
#pragma unroll
            for (int kc = 0; kc < 2; ++kc)
                bk[u][kc] = *(const bf16x8*)(kbh +
                    ((size_t)bh * L_ + j0 + 16 * u + n) * HD_ + kc * 32 + 8 * q4);

        // ---- rel: R = Q @ Eband^T, stored transposed band[p][row] ----
        const int rbase = j0 - ib + 992;   // Eb row = rbase + p, p in [0,95]
#pragma unroll
        for (int up = 0; up < 6; ++up) {
            f32x4 rc[2] = {};
#pragma unroll
            for (int kc = 0; kc < 2; ++kc) {
                const bf16x8 be = *(const bf16x8*)(Eb +
                    ((size_t)(rbase + 16 * up + n)) * HD_ + kc * 32 + 8 * q4);
#pragma unroll
                for (int m = 0; m < 2; ++m)
                    rc[m] = __builtin_amdgcn_mfma_f32_16x16x32_bf16(
                        aq[m][kc], be, rc[m], 0, 0, 0);
            }
#pragma unroll
            for (int m = 0; m < 2; ++m) {
                bf16x4 pk;
#pragma unroll
                for (int r = 0; r < 4; ++r) pk[r] = (bf16_t)rc[m][r];
                *(bf16x4*)&band[(size_t)(16 * up + n) * 40 + 16 * m + 4 * q4] = pk;
            }
        }

        // ---- S = Q K^T ----
        f32x4 s[2][4] = {};
#pragma unroll
        for (int u = 0; u < 4; ++u)
#pragma unroll
            for (int kc = 0; kc < 2; ++kc)
#pragma unroll
                for (int m = 0; m < 2; ++m)
                    s[m][u] = __builtin_amdgcn_mfma_f32_16x16x32_bf16(
                        aq[m][kc], bk[u][kc], s[m][u], 0, 0, 0);

        // ---- prefetch V fragments ----
        bf16x8 vf[4][2];
#pragma unroll
        for (int u = 0; u < 4; ++u)
#pragma unroll
            for (int kc = 0; kc < 2; ++kc)
                vf[u][kc] = *(const bf16x8*)(vbase +
                    ((size_t)(16 * u + n)) * L_ + j0 + kc * 32 + 8 * q4);

        // ---- skew add: S[row][jj] += band[jj - row + 31][row] ----
#pragma unroll
        for (int m = 0; m < 2; ++m)
#pragma unroll
            for (int u = 0; u < 4; ++u)
#pragma unroll
                for (int r = 0; r < 4; ++r) {
                    const int row = 16 * m + 4 * q4 + r;
                    s[m][u][r] +=
                        (float)band[(size_t)(16 * u + n - row + 31) * 40 + row];
                }

        // ---- online softmax: max via DPP (VALU pipe), exp, rescale ----
        float al[2][4];
#pragma unroll
        for (int m = 0; m < 2; ++m) {
#pragma unroll
            for (int r = 0; r < 4; ++r) {
                float mt = fmaxf(fmaxf(s[m][0][r], s[m][1][r]),
                                 fmaxf(s[m][2][r], s[m][3][r]));
                mt = dpp_fmax<0x121>(mt);   // row_ror:1
                mt = dpp_fmax<0x122>(mt);   // row_ror:2
                mt = dpp_fmax<0x124>(mt);   // row_ror:4
                mt = dpp_fmax<0x128>(mt);   // row_ror:8
                const float mn = fmaxf(m_r[m][r], mt);
                al[m][r] = __expf(m_r[m][r] - mn);
                m_r[m][r] = mn;
#pragma unroll
                for (int u = 0; u < 4; ++u) {
                    s[m][u][r] = __expf(s[m][u][r] - mn);
                    o[m][u][r] *= al[m][r];
                }
            }
        }

        // ---- P -> LDS (stride 72), then A-frags ----
#pragma unroll
        for (int m = 0; m < 2; ++m)
#pragma unroll
            for (int u = 0; u < 4; ++u)
#pragma unroll
                for (int r = 0; r < 4; ++r)
                    ps[(size_t)(16 * m + 4 * q4 + r) * 72 + 16 * u + n] =
                        (bf16_t)s[m][u][r];

        bf16x8 pa[2][2];
#pragma unroll
        for (int m = 0; m < 2; ++m) {
            pa[m][0] = *(const bf16x8*)&ps[(size_t)(16 * m + n) * 72 + 8 * q4];
            pa[m][1] = *(const bf16x8*)&ps[(size_t)(16 * m + n) * 72 + 32 + 8 * q4];
        }

        // ---- row-sum via MFMA P @ ones (replaces 32 shuffle-adds) ----
#pragma unroll
        for (int m = 0; m < 2; ++m) {
            f32x4 z = {};
            z = __builtin_amdgcn_mfma_f32_16x16x32_bf16(pa[m][0], ones, z, 0, 0, 0);
            z = __builtin_amdgcn_mfma_f32_16x16x32_bf16(pa[m][1], ones, z, 0, 0, 0);
#pragma unroll
            for (int r = 0; r < 4; ++r)
                l_r[m][r] = l_r[m][r] * al[m][r] + z[r];
        }

        // ---- O += P V ----
#pragma unroll
        for (int u = 0; u < 4; ++u)
#pragma unroll
            for (int kc = 0; kc < 2; ++kc)
#pragma unroll
                for (int m = 0; m < 2; ++m)
                    o[m][u] = __builtin_amdgcn_mfma_f32_16x16x32_bf16(
                        pa[m][kc], vf[u][kc], o[m][u], 0, 0, 0);
    }

    // ---- 4-way cross-wave merge ----
    __syncthreads();
#pragma unroll
    for (int m = 0; m < 2; ++m)
#pragma unroll
        for (int u = 0; u < 4; ++u)
#pragma unroll
            for (int r = 0; r < 4; ++r)
                Om[w][16 * m + 4 * q4 + r][16 * u + n] = o[m][u][r];
    if (n == 0) {
#pragma unroll
        for (int m = 0; m < 2; ++m)
#pragma unroll
            for (int r = 0; r < 4; ++r) {
                ml[w][16 * m + 4 * q4 + r][0] = m_r[m][r];
                ml[w][16 * m + 4 * q4 + r][1] = l_r[m][r];
            }
    }
    __syncthreads();

    {
        const int row = tid >> 3;          // 0..31
        const int c0 = (tid & 7) * 8;      // 0..56
        const float m0v = ml[0][row][0], m1v = ml[1][row][0];
        const float m2v = ml[2][row][0], m3v = ml[3][row][0];
        const float ms = fmaxf(fmaxf(m0v, m1v), fmaxf(m2v, m3v));
        const float a0 = __expf(m0v - ms), a1 = __expf(m1v - ms);
        const float a2 = __expf(m2v - ms), a3 = __expf(m3v - ms);
        const float inv = 1.f / (a0 * ml[0][row][1] + a1 * ml[1][row][1] +
                                 a2 * ml[2][row][1] + a3 * ml[3][row][1]);
        bf16_t* dst = ctx + ((size_t)(b * L_ + ib + row)) * D_ + h * HD_ + c0;
#pragma unroll
        for (int cc = 0; cc < 8; ++cc) {
            const int col = c0 + cc;
            const float val = (a0 * Om[0][row][col] + a1 * Om[1][row][col] +
                               a2 * Om[2][row][col] + a3 * Om[3][row][col]) * inv;
            dst[cc] = (bf16_t)val;
        }
    }
}

// ---------------------------------------------------------------------------
extern "C" void kernel_launch(void* const* d_in, const int* in_sizes, int n_in,
                              void* d_out, int out_size, void* d_ws,
                              size_t ws_size, hipStream_t stream) {
    const float* x   = (const float*)d_in[0];
    const float* Wq  = (const float*)d_in[1];
    const float* bq  = (const float*)d_in[2];
    const float* Wk  = (const float*)d_in[3];
    const float* bk  = (const float*)d_in[4];
    const float* Wv  = (const float*)d_in[5];
    const float* bv  = (const float*)d_in[6];
    const float* Wo  = (const float*)d_in[7];
    const float* bo  = (const float*)d_in[8];
    const float* E   = (const float*)d_in[9];
    float* out = (float*)d_out;   // fp32 per reference (validated round 5)

    char* ws = (char*)d_ws;
    const size_t MB = 1024u * 1024u;
    bf16_t* xb   = (bf16_t*)(ws);             // 4 MB
    bf16_t* Wqb  = (bf16_t*)(ws + 4 * MB);    // 2 MB
    bf16_t* Wkb  = (bf16_t*)(ws + 6 * MB);    // 2 MB
    bf16_t* Wvb  = (bf16_t*)(ws + 8 * MB);    // 2 MB
    bf16_t* Wob  = (bf16_t*)(ws + 10 * MB);   // 2 MB
    bf16_t* qbh  = (bf16_t*)(ws + 12 * MB);   // 4 MB (BH,L,64), pre-scaled
    bf16_t* kbh  = (bf16_t*)(ws + 16 * MB);   // 4 MB (BH,L,64)
    bf16_t* vtb  = (bf16_t*)(ws + 20 * MB);   // 4 MB (BH,64,L) transposed
    bf16_t* ctxb = (bf16_t*)(ws + 24 * MB);   // 4 MB (B,L,D)
    bf16_t* Eb   = (bf16_t*)(ws + 28 * MB);   // 0.25 MB (2048x64)

    prep_kernel<<<6656, 256, 0, stream>>>(x, Wq, Wk, Wv, Wo, E,
                                          xb, Wqb, Wkb, Wvb, Wob, Eb);

    dim3 gq(D_ / 64, (B_ * L_) / 64, 3);  // 1536 blocks
    qkv_gemm_kernel<<<gq, 256, 0, stream>>>(xb, Wqb, Wkb, Wvb, bq, bk, bv,
                                            qbh, kbh, vtb);

    dim3 ga(L_ / 32, B_ * H_);  // 1024 blocks
    fattn_kernel<<<ga, 256, 0, stream>>>(qbh, kbh, vtb, Eb, ctxb);

    dim3 gg(D_ / 64, (B_ * L_) / 64);  // 512 blocks
    out_gemm_kernel<<<gg, 256, 0, stream>>>(ctxb, Wob, bo, out);
}